// Round 11
// baseline (335.875 us; speedup 1.0000x reference)
//
#include <hip/hip_runtime.h>

#define B_DIM 2048
#define IN_DIM 1024
#define OUT_DIM 1024
#define K_KNOTS 20
#define KR (IN_DIM * K_KNOTS)   // 20480 reduction dim
#define TM 128
#define TN 128
#define BK 128
#define KSPLIT 4
#define OUT_ELEMS (B_DIM * OUT_DIM)
#define MT_TILES (B_DIM / TM)   // 16
#define NT_TILES (OUT_DIM / TN) // 8
#define NCELLS (MT_TILES * NT_TILES)                // 128
#define GEMM_BLOCKS (MT_TILES * NT_TILES * KSPLIT)  // 512

// LDS map (shorts): As half0 @0, As half1 @8192, Bs half0 @16384, Bs half1 @24576
#define LDS_AS0 0
#define LDS_AS1 8192
#define LDS_BS0 16384
#define LDS_BS1 24576

#define NB_QUADS (B_DIM * IN_DIM * 5)             // 10,485,760 threads (4 knots each)
#define NB_BASIS_BLK (NB_QUADS / 256)             // 40960 blocks
#define NW4 (OUT_DIM * KR / 8)                    // 2,621,440 uint4 outputs
#define NB_W_BLK (NW4 / 256)                      // 10240 blocks

typedef __bf16 bf16x8 __attribute__((ext_vector_type(8)));
typedef float  f32x4  __attribute__((ext_vector_type(4)));

__device__ __forceinline__ unsigned short f2bf(float f) {
    unsigned int u = __float_as_uint(f);
    unsigned int r = u + 0x7fffu + ((u >> 16) & 1u);   // RNE; no NaN inputs here
    return (unsigned short)(r >> 16);
}

__device__ __forceinline__ unsigned int pack2(float lo, float hi) {
    return (unsigned int)f2bf(lo) | ((unsigned int)f2bf(hi) << 16);
}

__device__ __forceinline__ void async_load16(const void* g, void* l) {
    __builtin_amdgcn_global_load_lds(
        (const __attribute__((address_space(1))) void*)g,
        (__attribute__((address_space(3))) void*)l,
        16, 0, 0);
}

// ---------------- zero the output (atomic fallback path only) ----------------
__global__ void zero_out_kernel(float* out) {
    int idx = (blockIdx.x * 256 + threadIdx.x) * 4;
    float4 z = {0.f, 0.f, 0.f, 0.f};
    *(float4*)(out + idx) = z;
}

// ------- merged prep: basis bf16 (B,IN*K) + W fp32->bf16 + counter zero ------
__global__ void __launch_bounds__(256) prep_kernel(
        const float* __restrict__ x,
        const float4* __restrict__ Wsrc,
        const float* __restrict__ knots,
        uint2* __restrict__ basis_out,
        uint4* __restrict__ w_out,
        int* counters) {                    // may be nullptr (atomic path)
    if (blockIdx.x < NB_BASIS_BLK) {
        unsigned int n = blockIdx.x * 256 + threadIdx.x;   // quad index
        unsigned int q  = n % 5u;                          // which knot-quad
        unsigned int bi = n / 5u;                          // b*1024 + i
        float t0 = knots[0];
        float h  = knots[1] - t0;
        float invh = 1.0f / h;
        float xv = x[bi];
        float k0 = (float)(4 * q);
        float v[4];
#pragma unroll
        for (int j = 0; j < 4; ++j) {
            float t = __builtin_fmaf(k0 + (float)j, h, t0);
            float d = (xv - t) * invh;
            v[j] = __expf(-0.5f * d * d);
        }
        uint2 o;
        o.x = pack2(v[0], v[1]);
        o.y = pack2(v[2], v[3]);
        basis_out[n] = o;
    } else if (blockIdx.x < NB_BASIS_BLK + NB_W_BLK) {
        unsigned int t = (blockIdx.x - NB_BASIS_BLK) * 256 + threadIdx.x;
        float4 a = Wsrc[2 * t];
        float4 b = Wsrc[2 * t + 1];
        uint4 o;
        o.x = pack2(a.x, a.y);
        o.y = pack2(a.z, a.w);
        o.z = pack2(b.x, b.y);
        o.w = pack2(b.z, b.w);
        w_out[t] = o;
    } else {
        // one extra block: zero the completion counters (ws is 0xAA-poisoned)
        if (counters && threadIdx.x < NCELLS) counters[threadIdx.x] = 0;
    }
}

// ---------------- bf16 MFMA GEMM + fused K-split reduction -------------------
// Compute structure identical to R8/R10 (measured best: 96.2 us, 0 conflicts,
// MfmaUtil 39%). Epilogue: every z-block stores its partial slice, then
// last-arriving block per (mt,nt) cell (device-scope counter) sums the KS
// slices and writes the final output -- removes the kan_reduce dispatch.
template <int KS>
__global__ void __launch_bounds__(256)
kan_gemm_fused(const unsigned short* __restrict__ Ab,  // (2048, 20480) bf16
               const unsigned short* __restrict__ Bb,  // (1024, 20480) bf16
               float* __restrict__ part,               // KS * OUT_ELEMS scratch
               float* __restrict__ out,                // final (B, OUT)
               int* __restrict__ counters) {           // NCELLS ints, zeroed
    __shared__ __align__(16) unsigned short lds[32768];   // 64 KB
    __shared__ int is_last;

    const int KPBk = KR / KS;
    const int id   = blockIdx.x;
    const int xcd  = id & 7;
    const int ord  = id >> 3;           // 0..63
    const int mt   = xcd * 2 + (ord & 1);
    const int nt   = (ord >> 1) & (NT_TILES - 1);
    const int z    = ord >> 4;          // 0..KS-1
    const int m0 = mt * TM;
    const int n0 = nt * TN;
    const int k0 = z * KPBk;

    const int tid  = threadIdx.x;
    const int wave = tid >> 6;
    const int lane = tid & 63;
    const int wm = wave & 1;          // 2x2 wave grid -> each wave does 64x64
    const int wn = wave >> 1;

    const int srow = lane >> 3;                 // staging: row within 8-row chunk
    const int scol = ((lane & 7) ^ srow) * 8;   // staging: swizzled element col

    f32x4 acc[4][4];
#pragma unroll
    for (int i = 0; i < 4; ++i)
#pragma unroll
        for (int j = 0; j < 4; ++j) acc[i][j] = (f32x4){0.f, 0.f, 0.f, 0.f};

    for (int kt = 0; kt < KPBk; kt += BK) {
        const int kb = k0 + kt;
        __syncthreads();   // previous iteration's ds_reads done before overwrite
#pragma unroll
        for (int c = 0; c < 4; ++c) {
            const int chunk = wave * 4 + c;            // 16 chunks of 8 rows
            const int r = chunk * 8 + srow;
            const unsigned short* arow = Ab + (size_t)(m0 + r) * KR + kb + scol;
            const unsigned short* brow = Bb + (size_t)(n0 + r) * KR + kb + scol;
            unsigned short* slot = &lds[chunk * 512];
            async_load16(arow,      slot + LDS_AS0);
            async_load16(arow + 64, slot + LDS_AS1);
            async_load16(brow,      slot + LDS_BS0);
            async_load16(brow + 64, slot + LDS_BS1);
        }
        __syncthreads();   // compiler drains vmcnt(0) before barrier

        const int quad = lane >> 4;
        const int r15  = lane & 15;
        const int r7   = lane & 7;
#pragma unroll
        for (int s = 0; s < 4; ++s) {
            const int abase = (s >> 1) ? LDS_AS1 : LDS_AS0;
            const int bbase = (s >> 1) ? LDS_BS1 : LDS_BS0;
            const int cg = (s & 1) * 4 + quad;         // colgroup 0..7 in half
            const int xo = (cg ^ r7) * 8;              // unswizzled element offset
            bf16x8 af[4], bfv[4];
#pragma unroll
            for (int i = 0; i < 4; ++i) {
                af[i]  = *(const bf16x8*)&lds[abase + (wm * 64 + i * 16 + r15) * 64 + xo];
                bfv[i] = *(const bf16x8*)&lds[bbase + (wn * 64 + i * 16 + r15) * 64 + xo];
            }
#pragma unroll
            for (int i = 0; i < 4; ++i)
#pragma unroll
                for (int j = 0; j < 4; ++j)
                    acc[i][j] = __builtin_amdgcn_mfma_f32_16x16x32_bf16(
                        af[i], bfv[j], acc[i][j], 0, 0, 0);
        }
    }

    // ---- epilogue: store partial slice (C/D: col=lane&15, row=quad*4+reg) ----
    float* dst = part + (size_t)z * OUT_ELEMS;
    const int quad = lane >> 4;
    const int col  = lane & 15;
#pragma unroll
    for (int i = 0; i < 4; ++i)
#pragma unroll
        for (int j = 0; j < 4; ++j)
#pragma unroll
            for (int r = 0; r < 4; ++r) {
                const int row = m0 + wm * 64 + i * 16 + quad * 4 + r;
                const int c   = n0 + wn * 64 + j * 16 + col;
                dst[(size_t)row * OUT_DIM + c] = acc[i][j][r];
            }

    // ---- last block per cell reduces the KS slices into out ----
    __threadfence();                       // release partial stores (device scope)
    if (tid == 0) {
        int old = atomicAdd(&counters[mt * NT_TILES + nt], 1);
        is_last = (old == KS - 1);
    }
    __syncthreads();
    if (is_last) {
        __threadfence();                   // acquire other blocks' partials
#pragma unroll
        for (int i = 0; i < 4; ++i)
#pragma unroll
            for (int j = 0; j < 4; ++j)
#pragma unroll
                for (int r = 0; r < 4; ++r) {
                    const int row = m0 + wm * 64 + i * 16 + quad * 4 + r;
                    const int c   = n0 + wn * 64 + j * 16 + col;
                    const size_t off = (size_t)row * OUT_DIM + c;
                    float s = part[off];
#pragma unroll
                    for (int zz = 1; zz < KS; ++zz)
                        s += part[(size_t)zz * OUT_ELEMS + off];
                    out[off] = s;
                }
    }
}

// ---------------- atomic-path gemm (mid fallback, R8 structure) --------------
template <int KS>
__global__ void __launch_bounds__(256)
kan_gemm_atomic(const unsigned short* __restrict__ Ab,
                const unsigned short* __restrict__ Bb,
                float* __restrict__ out) {
    __shared__ __align__(16) unsigned short lds[32768];

    const int KPBk = KR / KS;
    const int id   = blockIdx.x;
    const int xcd  = id & 7;
    const int ord  = id >> 3;
    const int mt   = xcd * 2 + (ord & 1);
    const int nt   = (ord >> 1) & (NT_TILES - 1);
    const int z    = ord >> 4;
    const int m0 = mt * TM;
    const int n0 = nt * TN;
    const int k0 = z * KPBk;

    const int tid  = threadIdx.x;
    const int wave = tid >> 6;
    const int lane = tid & 63;
    const int wm = wave & 1;
    const int wn = wave >> 1;

    const int srow = lane >> 3;
    const int scol = ((lane & 7) ^ srow) * 8;

    f32x4 acc[4][4];
#pragma unroll
    for (int i = 0; i < 4; ++i)
#pragma unroll
        for (int j = 0; j < 4; ++j) acc[i][j] = (f32x4){0.f, 0.f, 0.f, 0.f};

    for (int kt = 0; kt < KPBk; kt += BK) {
        const int kb = k0 + kt;
        __syncthreads();
#pragma unroll
        for (int c = 0; c < 4; ++c) {
            const int chunk = wave * 4 + c;
            const int r = chunk * 8 + srow;
            const unsigned short* arow = Ab + (size_t)(m0 + r) * KR + kb + scol;
            const unsigned short* brow = Bb + (size_t)(n0 + r) * KR + kb + scol;
            unsigned short* slot = &lds[chunk * 512];
            async_load16(arow,      slot + LDS_AS0);
            async_load16(arow + 64, slot + LDS_AS1);
            async_load16(brow,      slot + LDS_BS0);
            async_load16(brow + 64, slot + LDS_BS1);
        }
        __syncthreads();

        const int quad = lane >> 4;
        const int r15  = lane & 15;
        const int r7   = lane & 7;
#pragma unroll
        for (int s = 0; s < 4; ++s) {
            const int abase = (s >> 1) ? LDS_AS1 : LDS_AS0;
            const int bbase = (s >> 1) ? LDS_BS1 : LDS_BS0;
            const int cg = (s & 1) * 4 + quad;
            const int xo = (cg ^ r7) * 8;
            bf16x8 af[4], bfv[4];
#pragma unroll
            for (int i = 0; i < 4; ++i) {
                af[i]  = *(const bf16x8*)&lds[abase + (wm * 64 + i * 16 + r15) * 64 + xo];
                bfv[i] = *(const bf16x8*)&lds[bbase + (wn * 64 + i * 16 + r15) * 64 + xo];
            }
#pragma unroll
            for (int i = 0; i < 4; ++i)
#pragma unroll
                for (int j = 0; j < 4; ++j)
                    acc[i][j] = __builtin_amdgcn_mfma_f32_16x16x32_bf16(
                        af[i], bfv[j], acc[i][j], 0, 0, 0);
        }
    }

    const int quad = lane >> 4;
    const int col  = lane & 15;
#pragma unroll
    for (int i = 0; i < 4; ++i)
#pragma unroll
        for (int j = 0; j < 4; ++j)
#pragma unroll
            for (int r = 0; r < 4; ++r) {
                const int row = m0 + wm * 64 + i * 16 + quad * 4 + r;
                const int c   = n0 + wn * 64 + j * 16 + col;
                atomicAdd(&out[(size_t)row * OUT_DIM + c], acc[i][j][r]);
            }
}

// ---------------- fallback (ws too small): correctness-only fp32 -------------
__global__ void kan_fallback(const float* __restrict__ x,
                             const float* __restrict__ W,
                             const float* __restrict__ knots,
                             float* __restrict__ out) {
    __shared__ float basis[256 * K_KNOTS];
    const int b = blockIdx.x;
    const int o = blockIdx.y * blockDim.x + threadIdx.x;
    const float invh = 1.0f / (knots[1] - knots[0]);
    const float* w = W + (size_t)o * KR;
    float sum = 0.f;
    for (int i0 = 0; i0 < IN_DIM; i0 += 256) {
        __syncthreads();
        for (int idx = threadIdx.x; idx < 256 * K_KNOTS; idx += blockDim.x) {
            const int i = i0 + idx / K_KNOTS;
            const int k = idx % K_KNOTS;
            const float d = (x[(size_t)b * IN_DIM + i] - knots[k]) * invh;
            basis[idx] = __expf(-0.5f * d * d);
        }
        __syncthreads();
        for (int r = 0; r < 256 * K_KNOTS; ++r)
            sum += basis[r] * w[(size_t)i0 * K_KNOTS + r];
    }
    out[(size_t)b * OUT_DIM + o] = sum;
}

extern "C" void kernel_launch(void* const* d_in, const int* in_sizes, int n_in,
                              void* d_out, int out_size, void* d_ws, size_t ws_size,
                              hipStream_t stream) {
    const float* x     = (const float*)d_in[0];
    const float* W     = (const float*)d_in[1];
    const float* knots = (const float*)d_in[2];
    float* out = (float*)d_out;

    const size_t basis_bytes = (size_t)B_DIM * KR * 2;              // 80 MiB
    const size_t wb_bytes    = (size_t)OUT_DIM * KR * 2;            // 40 MiB
    const size_t part_bytes  = (size_t)KSPLIT * OUT_ELEMS * 4;      // 32 MiB
    const size_t ctr_bytes   = (size_t)NCELLS * 4;                  // 512 B

    unsigned short* Ab = (unsigned short*)d_ws;
    unsigned short* Bb = (unsigned short*)((char*)d_ws + basis_bytes);
    float* part = (float*)((char*)d_ws + basis_bytes + wb_bytes);
    int* counters = (int*)((char*)d_ws + basis_bytes + wb_bytes + part_bytes);

    if (ws_size >= basis_bytes + wb_bytes + part_bytes + ctr_bytes) {
        prep_kernel<<<dim3(NB_BASIS_BLK + NB_W_BLK + 1), dim3(256), 0, stream>>>(
            x, (const float4*)W, knots, (uint2*)Ab, (uint4*)Bb, counters);
        kan_gemm_fused<KSPLIT><<<dim3(GEMM_BLOCKS), dim3(256), 0, stream>>>(
            Ab, Bb, part, out, counters);
    } else if (ws_size >= basis_bytes + wb_bytes) {
        zero_out_kernel<<<dim3(OUT_ELEMS / (256 * 4)), dim3(256), 0, stream>>>(out);
        prep_kernel<<<dim3(NB_BASIS_BLK + NB_W_BLK + 1), dim3(256), 0, stream>>>(
            x, (const float4*)W, knots, (uint2*)Ab, (uint4*)Bb, nullptr);
        kan_gemm_atomic<KSPLIT><<<dim3(GEMM_BLOCKS), dim3(256), 0, stream>>>(Ab, Bb, out);
    } else {
        kan_fallback<<<dim3(B_DIM, OUT_DIM / 256), dim3(256), 0, stream>>>(x, W, knots, out);
    }
}

// Round 12
// 251.110 us; speedup vs baseline: 1.3376x; 1.3376x over previous
//
#include <hip/hip_runtime.h>

#define B_DIM 2048
#define IN_DIM 1024
#define OUT_DIM 1024
#define K_KNOTS 20
#define KR (IN_DIM * K_KNOTS)   // 20480 reduction dim
#define TM 128
#define TN 128
#define BK 128
#define KSPLIT 4
#define KPB (KR / KSPLIT)       // 5120 -> 40 iters of BK=128
#define OUT_ELEMS (B_DIM * OUT_DIM)
#define MT_TILES (B_DIM / TM)   // 16
#define NT_TILES (OUT_DIM / TN) // 8
#define GEMM_BLOCKS (MT_TILES * NT_TILES * KSPLIT)  // 512

// LDS map (shorts): As half0 @0, As half1 @8192, Bs half0 @16384, Bs half1 @24576
#define LDS_AS0 0
#define LDS_AS1 8192
#define LDS_BS0 16384
#define LDS_BS1 24576

#define NB_QUADS (B_DIM * IN_DIM * 5)             // 10,485,760 threads (4 knots each)
#define NB_BASIS_BLK (NB_QUADS / 256)             // 40960 blocks
#define NW4 (OUT_DIM * KR / 8)                    // 2,621,440 uint4 outputs
#define NB_W_BLK (NW4 / 256)                      // 10240 blocks

typedef __bf16 bf16x8 __attribute__((ext_vector_type(8)));
typedef float  f32x4  __attribute__((ext_vector_type(4)));

__device__ __forceinline__ unsigned short f2bf(float f) {
    unsigned int u = __float_as_uint(f);
    unsigned int r = u + 0x7fffu + ((u >> 16) & 1u);   // RNE; no NaN inputs here
    return (unsigned short)(r >> 16);
}

__device__ __forceinline__ unsigned int pack2(float lo, float hi) {
    return (unsigned int)f2bf(lo) | ((unsigned int)f2bf(hi) << 16);
}

__device__ __forceinline__ void async_load16(const void* g, void* l) {
    __builtin_amdgcn_global_load_lds(
        (const __attribute__((address_space(1))) void*)g,
        (__attribute__((address_space(3))) void*)l,
        16, 0, 0);
}

// ---------------- zero the output (atomic fallback path only) ----------------
__global__ void zero_out_kernel(float* out) {
    int idx = (blockIdx.x * 256 + threadIdx.x) * 4;
    float4 z = {0.f, 0.f, 0.f, 0.f};
    *(float4*)(out + idx) = z;
}

// ------- merged prep: basis bf16 (B,IN*K) + W fp32->bf16, one dispatch -------
__global__ void __launch_bounds__(256) prep_kernel(
        const float* __restrict__ x,
        const float4* __restrict__ Wsrc,
        const float* __restrict__ knots,
        uint2* __restrict__ basis_out,
        uint4* __restrict__ w_out) {
    if (blockIdx.x < NB_BASIS_BLK) {
        unsigned int n = blockIdx.x * 256 + threadIdx.x;   // quad index
        unsigned int q  = n % 5u;                          // which knot-quad
        unsigned int bi = n / 5u;                          // b*1024 + i
        float t0 = knots[0];
        float h  = knots[1] - t0;
        float invh = 1.0f / h;
        float xv = x[bi];
        float k0 = (float)(4 * q);
        float v[4];
#pragma unroll
        for (int j = 0; j < 4; ++j) {
            float t = __builtin_fmaf(k0 + (float)j, h, t0);
            float d = (xv - t) * invh;
            v[j] = __expf(-0.5f * d * d);
        }
        uint2 o;
        o.x = pack2(v[0], v[1]);
        o.y = pack2(v[2], v[3]);
        basis_out[n] = o;
    } else {
        unsigned int t = (blockIdx.x - NB_BASIS_BLK) * 256 + threadIdx.x;
        float4 a = Wsrc[2 * t];
        float4 b = Wsrc[2 * t + 1];
        uint4 o;
        o.x = pack2(a.x, a.y);
        o.y = pack2(a.z, a.w);
        o.z = pack2(b.x, b.y);
        o.w = pack2(b.z, b.w);
        w_out[t] = o;
    }
}

// ---------------- bf16 MFMA GEMM: C[b,o] += sum_r A[b,r]*W[o,r] --------------
// R8/R10 configuration -- the measured best (96.2 us, MfmaUtil 39%, 0 LDS
// conflicts). BK=128 staged as TWO 64-col half-tiles, each in the verified
// conflict-free layout: row stride 64 shorts, 8 col-slots, XOR swizzle
// (lane&7)^srow; reads vary col-slot with lane>>4, row with lane&15.
// Flat LDS + explicit offsets (2-D array form core-dumped in R7).
// 16x16x32 MFMA (R9: 32x32x16 = no MFMA-busy win + conflicts).
// Separate reduce dispatch (R11: fused last-block reduction with
// device-scope __threadfence = 2x regression; fences don't belong here).
template <int KS, bool ATOMIC>
__global__ void __launch_bounds__(256)
kan_gemm(const unsigned short* __restrict__ Ab,   // (2048, 20480) bf16 row-major
         const unsigned short* __restrict__ Bb,   // (1024, 20480) bf16 row-major
         float* __restrict__ out) {               // out or partial base
    __shared__ __align__(16) unsigned short lds[32768];   // 64 KB

    const int KPBk = KR / KS;
    const int id   = blockIdx.x;
    const int xcd  = id & 7;
    const int ord  = id >> 3;           // 0..63
    const int mt   = xcd * 2 + (ord & 1);
    const int nt   = (ord >> 1) & (NT_TILES - 1);
    const int z    = ord >> 4;          // 0..KS-1
    const int m0 = mt * TM;
    const int n0 = nt * TN;
    const int k0 = z * KPBk;

    const int tid  = threadIdx.x;
    const int wave = tid >> 6;
    const int lane = tid & 63;
    const int wm = wave & 1;          // 2x2 wave grid -> each wave does 64x64
    const int wn = wave >> 1;

    const int srow = lane >> 3;                 // staging: row within 8-row chunk
    const int scol = ((lane & 7) ^ srow) * 8;   // staging: swizzled element col

    f32x4 acc[4][4];
#pragma unroll
    for (int i = 0; i < 4; ++i)
#pragma unroll
        for (int j = 0; j < 4; ++j) acc[i][j] = (f32x4){0.f, 0.f, 0.f, 0.f};

    for (int kt = 0; kt < KPBk; kt += BK) {
        const int kb = k0 + kt;
        __syncthreads();   // previous iteration's ds_reads done before overwrite
#pragma unroll
        for (int c = 0; c < 4; ++c) {
            const int chunk = wave * 4 + c;            // 16 chunks of 8 rows
            const int r = chunk * 8 + srow;
            const unsigned short* arow = Ab + (size_t)(m0 + r) * KR + kb + scol;
            const unsigned short* brow = Bb + (size_t)(n0 + r) * KR + kb + scol;
            unsigned short* slot = &lds[chunk * 512];
            async_load16(arow,      slot + LDS_AS0);
            async_load16(arow + 64, slot + LDS_AS1);
            async_load16(brow,      slot + LDS_BS0);
            async_load16(brow + 64, slot + LDS_BS1);
        }
        __syncthreads();   // compiler drains vmcnt(0) before barrier

        const int quad = lane >> 4;
        const int r15  = lane & 15;
        const int r7   = lane & 7;
#pragma unroll
        for (int s = 0; s < 4; ++s) {
            const int abase = (s >> 1) ? LDS_AS1 : LDS_AS0;
            const int bbase = (s >> 1) ? LDS_BS1 : LDS_BS0;
            const int cg = (s & 1) * 4 + quad;         // colgroup 0..7 in half
            const int xo = (cg ^ r7) * 8;              // unswizzled element offset
            bf16x8 af[4], bfv[4];
#pragma unroll
            for (int i = 0; i < 4; ++i) {
                af[i]  = *(const bf16x8*)&lds[abase + (wm * 64 + i * 16 + r15) * 64 + xo];
                bfv[i] = *(const bf16x8*)&lds[bbase + (wn * 64 + i * 16 + r15) * 64 + xo];
            }
#pragma unroll
            for (int i = 0; i < 4; ++i)
#pragma unroll
                for (int j = 0; j < 4; ++j)
                    acc[i][j] = __builtin_amdgcn_mfma_f32_16x16x32_bf16(
                        af[i], bfv[j], acc[i][j], 0, 0, 0);
        }
    }

    // epilogue: C/D layout col=lane&15, row=(lane>>4)*4+reg
    float* dst = ATOMIC ? out : out + (size_t)z * OUT_ELEMS;
    const int quad = lane >> 4;
    const int col  = lane & 15;
#pragma unroll
    for (int i = 0; i < 4; ++i)
#pragma unroll
        for (int j = 0; j < 4; ++j)
#pragma unroll
            for (int r = 0; r < 4; ++r) {
                const int row = m0 + wm * 64 + i * 16 + quad * 4 + r;
                const int c   = n0 + wn * 64 + j * 16 + col;
                if (ATOMIC)
                    atomicAdd(&dst[(size_t)row * OUT_DIM + c], acc[i][j][r]);
                else
                    dst[(size_t)row * OUT_DIM + c] = acc[i][j][r];
            }
}

// ---------------- reduce KS partial slices -> out ----------------------------
template <int KS>
__global__ void kan_reduce(const float* __restrict__ part, float* __restrict__ out) {
    const int idx = (blockIdx.x * 256 + threadIdx.x) * 4;
    f32x4 s = *(const f32x4*)(part + idx);
#pragma unroll
    for (int z = 1; z < KS; ++z)
        s += *(const f32x4*)(part + (size_t)z * OUT_ELEMS + idx);
    *(f32x4*)(out + idx) = s;
}

// ---------------- fallback (ws too small): correctness-only fp32 -------------
__global__ void kan_fallback(const float* __restrict__ x,
                             const float* __restrict__ W,
                             const float* __restrict__ knots,
                             float* __restrict__ out) {
    __shared__ float basis[256 * K_KNOTS];
    const int b = blockIdx.x;
    const int o = blockIdx.y * blockDim.x + threadIdx.x;
    const float invh = 1.0f / (knots[1] - knots[0]);
    const float* w = W + (size_t)o * KR;
    float sum = 0.f;
    for (int i0 = 0; i0 < IN_DIM; i0 += 256) {
        __syncthreads();
        for (int idx = threadIdx.x; idx < 256 * K_KNOTS; idx += blockDim.x) {
            const int i = i0 + idx / K_KNOTS;
            const int k = idx % K_KNOTS;
            const float d = (x[(size_t)b * IN_DIM + i] - knots[k]) * invh;
            basis[idx] = __expf(-0.5f * d * d);
        }
        __syncthreads();
        for (int r = 0; r < 256 * K_KNOTS; ++r)
            sum += basis[r] * w[(size_t)i0 * K_KNOTS + r];
    }
    out[(size_t)b * OUT_DIM + o] = sum;
}

extern "C" void kernel_launch(void* const* d_in, const int* in_sizes, int n_in,
                              void* d_out, int out_size, void* d_ws, size_t ws_size,
                              hipStream_t stream) {
    const float* x     = (const float*)d_in[0];
    const float* W     = (const float*)d_in[1];
    const float* knots = (const float*)d_in[2];
    float* out = (float*)d_out;

    const size_t basis_bytes = (size_t)B_DIM * KR * 2;              // 80 MiB
    const size_t wb_bytes    = (size_t)OUT_DIM * KR * 2;            // 40 MiB
    const size_t part_bytes  = (size_t)KSPLIT * OUT_ELEMS * 4;      // 32 MiB

    unsigned short* Ab = (unsigned short*)d_ws;
    unsigned short* Bb = (unsigned short*)((char*)d_ws + basis_bytes);
    float* part = (float*)((char*)d_ws + basis_bytes + wb_bytes);

    if (ws_size >= basis_bytes + wb_bytes + part_bytes) {
        prep_kernel<<<dim3(NB_BASIS_BLK + NB_W_BLK), dim3(256), 0, stream>>>(
            x, (const float4*)W, knots, (uint2*)Ab, (uint4*)Bb);
        kan_gemm<KSPLIT, false><<<dim3(GEMM_BLOCKS), dim3(256), 0, stream>>>(Ab, Bb, part);
        kan_reduce<KSPLIT><<<dim3(OUT_ELEMS / (256 * 4)), dim3(256), 0, stream>>>(part, out);
    } else if (ws_size >= basis_bytes + wb_bytes) {
        zero_out_kernel<<<dim3(OUT_ELEMS / (256 * 4)), dim3(256), 0, stream>>>(out);
        prep_kernel<<<dim3(NB_BASIS_BLK + NB_W_BLK), dim3(256), 0, stream>>>(
            x, (const float4*)W, knots, (uint2*)Ab, (uint4*)Bb);
        kan_gemm<KSPLIT, true><<<dim3(GEMM_BLOCKS), dim3(256), 0, stream>>>(Ab, Bb, out);
    } else {
        kan_fallback<<<dim3(B_DIM, OUT_DIM / 256), dim3(256), 0, stream>>>(x, W, knots, out);
    }
}